// Round 3
// baseline (127.886 us; speedup 1.0000x reference)
//
#include <hip/hip_runtime.h>

// query_depth_point: B=8, N=16384, M=2048, NSAMPLE=64, DIS_Z=0.5
// Wave-per-query: 64 lanes scan 64 candidates/iteration; ballot + prefix
// popcount assigns ordered output slots; wave-uniform early exit at 64 matches.
// Outputs are written as int32 (harness reads integer outputs via np.int32).

#define QDP_B 8
#define QDP_N 16384
#define QDP_M 2048
#define QDP_NS 64
#define QDP_DISZ 0.5f

__global__ __launch_bounds__(256) void QueryDepthPoint_kernel(
    const float* __restrict__ xyz1,   // (B,3,N)
    const float* __restrict__ xyz2,   // (B,3,M)
    int* __restrict__ out_idx,        // (B,M,NS) int32
    int* __restrict__ out_cnt)        // (B,M)    int32
{
    const int lane = threadIdx.x & 63;
    const int wid  = (blockIdx.x << 2) + (threadIdx.x >> 6);   // query id, 4 waves/block
    // grid exactly covers B*M waves (4096 blocks * 4 waves == 16384)

    const int b = wid >> 11;            // wid / M  (M = 2048)
    const int q = wid & (QDP_M - 1);    // wid % M

    const float zq = xyz2[b * 3 * QDP_M + 2 * QDP_M + q];
    const float* __restrict__ z1 = xyz1 + b * 3 * QDP_N + 2 * QDP_N;
    int* __restrict__ idx_out = out_idx + (size_t)wid * QDP_NS;

    int cnt    = 0;
    int firstv = 0;    // fill value for trailing slots (0 if no match at all)

    for (int c = 0; c < QDP_N; c += 64) {
        const float zj = z1[c + lane];
        const bool match = fabsf(zj - zq) < QDP_DISZ;
        const unsigned long long mask = __ballot(match);
        if (mask) {                                   // wave-uniform branch
            if (cnt == 0) {
                // first match index (wave-uniform): lowest set bit of mask
                firstv = c + (int)__builtin_ctzll(mask);
            }
            const unsigned long long below = mask & ((1ull << lane) - 1ull);
            const int slot = cnt + __popcll(below);
            if (match && slot < QDP_NS) {
                idx_out[slot] = c + lane;
            }
            cnt += __popcll(mask);
            if (cnt >= QDP_NS) { cnt = QDP_NS; break; }   // ball-query early stop
        }
    }

    // trailing slots [cnt, 64) get the first-match index (or 0 if cnt==0)
    if (lane >= cnt) idx_out[lane] = firstv;
    if (lane == 0)   out_cnt[wid] = cnt;
}

extern "C" void kernel_launch(void* const* d_in, const int* in_sizes, int n_in,
                              void* d_out, int out_size, void* d_ws, size_t ws_size,
                              hipStream_t stream) {
    const float* xyz1 = (const float*)d_in[0];   // (B,3,N) fp32
    const float* xyz2 = (const float*)d_in[1];   // (B,3,M) fp32
    int* out = (int*)d_out;                      // idx (B*M*64) then pts_cnt (B*M), int32

    int* out_idx = out;
    int* out_cnt = out + (size_t)QDP_B * QDP_M * QDP_NS;

    const int total_waves = QDP_B * QDP_M;           // 16384
    const int grid = total_waves / 4;                // 4 waves (256 thr) per block

    QueryDepthPoint_kernel<<<grid, 256, 0, stream>>>(xyz1, xyz2, out_idx, out_cnt);
}

// Round 4
// 77.401 us; speedup vs baseline: 1.6522x; 1.6522x over previous
//
#include <hip/hip_runtime.h>

// query_depth_point: B=8, N=16384, M=2048, NSAMPLE=64, DIS_Z=0.5
// Wave-per-query, float4 per lane: 256 candidates/iteration, 4 ballots,
// rank = cnt + matches-in-lower-lanes + own-lower-j matches (candidate order
// c+4*lane+j is lexicographic in (lane,j)). 1-deep prefetch hides L2 latency.
// Early exit at 64 matches. Outputs int32 (idx then pts_cnt).

#define QDP_B 8
#define QDP_N 16384
#define QDP_M 2048
#define QDP_NS 64
#define QDP_DISZ 0.5f

__global__ __launch_bounds__(256) void QueryDepthPoint_kernel(
    const float* __restrict__ xyz1,   // (B,3,N)
    const float* __restrict__ xyz2,   // (B,3,M)
    int* __restrict__ out_idx,        // (B,M,NS) int32
    int* __restrict__ out_cnt)        // (B,M)    int32
{
    const int lane = threadIdx.x & 63;
    const int wid  = (blockIdx.x << 2) + (threadIdx.x >> 6);   // 4 waves/block

    const int b = wid >> 11;            // wid / M  (M = 2048)
    const int q = wid & (QDP_M - 1);    // wid % M

    const float zq = xyz2[b * 3 * QDP_M + 2 * QDP_M + q];
    const float* __restrict__ z1 = xyz1 + b * 3 * QDP_N + 2 * QDP_N;
    int* __restrict__ idx_out = out_idx + (size_t)wid * QDP_NS;

    int cnt    = 0;
    int firstv = 0;

    // prefetch chunk 0
    float4 cur = ((const float4*)z1)[lane];            // candidates 4*lane .. 4*lane+3

    for (int c = 0; c < QDP_N; c += 256) {
        // issue next chunk's load before touching cur (overlaps with ballots)
        const int pc = (c + 256 < QDP_N) ? (c + 256) : 0;   // clamp; unused on last iter
        float4 nxt = ((const float4*)(z1 + pc))[lane];

        const bool m0 = fabsf(cur.x - zq) < QDP_DISZ;
        const bool m1 = fabsf(cur.y - zq) < QDP_DISZ;
        const bool m2 = fabsf(cur.z - zq) < QDP_DISZ;
        const bool m3 = fabsf(cur.w - zq) < QDP_DISZ;

        const unsigned long long b0 = __ballot(m0);
        const unsigned long long b1 = __ballot(m1);
        const unsigned long long b2 = __ballot(m2);
        const unsigned long long b3 = __ballot(m3);
        const unsigned long long any = b0 | b1 | b2 | b3;

        if (any) {                                     // wave-uniform
            const int nib = (int)m0 | ((int)m1 << 1) | ((int)m2 << 2) | ((int)m3 << 3);
            if (cnt == 0) {
                // first match = lowest (lane, j): lowest lane in any, then its lowest j
                const int l0   = (int)__builtin_ctzll(any);
                const int nib0 = __shfl(nib, l0);
                firstv = c + 4 * l0 + (int)__builtin_ctz((unsigned)nib0);
            }
            const unsigned long long below = (1ull << lane) - 1ull;
            int r = cnt + __popcll(b0 & below) + __popcll(b1 & below)
                        + __popcll(b2 & below) + __popcll(b3 & below);
            const int base = c + 4 * lane;
            if (m0) { if (r < QDP_NS) idx_out[r] = base + 0; r++; }
            if (m1) { if (r < QDP_NS) idx_out[r] = base + 1; r++; }
            if (m2) { if (r < QDP_NS) idx_out[r] = base + 2; r++; }
            if (m3) { if (r < QDP_NS) idx_out[r] = base + 3; r++; }
            cnt += __popcll(b0) + __popcll(b1) + __popcll(b2) + __popcll(b3);
            if (cnt >= QDP_NS) { cnt = QDP_NS; break; }
        }
        cur = nxt;
    }

    // trailing slots [cnt, 64) get the first-match index (0 if no match)
    if (lane >= cnt) idx_out[lane] = firstv;
    if (lane == 0)   out_cnt[wid] = cnt;
}

extern "C" void kernel_launch(void* const* d_in, const int* in_sizes, int n_in,
                              void* d_out, int out_size, void* d_ws, size_t ws_size,
                              hipStream_t stream) {
    const float* xyz1 = (const float*)d_in[0];   // (B,3,N) fp32
    const float* xyz2 = (const float*)d_in[1];   // (B,3,M) fp32
    int* out = (int*)d_out;                      // idx (B*M*64) then pts_cnt (B*M)

    int* out_idx = out;
    int* out_cnt = out + (size_t)QDP_B * QDP_M * QDP_NS;

    const int total_waves = QDP_B * QDP_M;           // 16384
    const int grid = total_waves / 4;                // 4 waves (256 thr) per block

    QueryDepthPoint_kernel<<<grid, 256, 0, stream>>>(xyz1, xyz2, out_idx, out_cnt);
}

// Round 5
// 72.756 us; speedup vs baseline: 1.7577x; 1.0638x over previous
//
#include <hip/hip_runtime.h>

// query_depth_point: B=8, N=16384, M=2048, NSAMPLE=64, DIS_Z=0.5
// Wave-per-query, 32 B/lane per iteration: 512 candidates/iter (candidate
// index = c + 8*lane + j, lexicographic in (lane, j)), 8 ballots, rank =
// cnt + matches-in-lower-lanes + own-lower-j matches. 1-deep prefetch (two
// independent 16 B loads in flight). Early exit at 64 matches.
// Outputs int32: idx (B,M,64) then pts_cnt (B,M).
// NOTE: measured bench floor is ~41 us of harness d_ws re-poison fill.

#define QDP_B 8
#define QDP_N 16384
#define QDP_M 2048
#define QDP_NS 64
#define QDP_DISZ 0.5f

__global__ __launch_bounds__(256) void QueryDepthPoint_kernel(
    const float* __restrict__ xyz1,   // (B,3,N)
    const float* __restrict__ xyz2,   // (B,3,M)
    int* __restrict__ out_idx,        // (B,M,NS) int32
    int* __restrict__ out_cnt)        // (B,M)    int32
{
    const int lane = threadIdx.x & 63;
    const int wid  = (blockIdx.x << 2) + (threadIdx.x >> 6);   // 4 waves/block

    const int b = wid >> 11;            // wid / M  (M = 2048)
    const int q = wid & (QDP_M - 1);    // wid % M

    const float zq = xyz2[b * 3 * QDP_M + 2 * QDP_M + q];
    const float* __restrict__ z1 = xyz1 + b * 3 * QDP_N + 2 * QDP_N;
    int* __restrict__ idx_out = out_idx + (size_t)wid * QDP_NS;

    int cnt    = 0;
    int firstv = 0;
    const unsigned long long below = (1ull << lane) - 1ull;

    // prefetch chunk 0: lane covers candidates 8*lane .. 8*lane+7
    const float* lptr = z1 + 8 * lane;
    float4 curA = ((const float4*)lptr)[0];
    float4 curB = ((const float4*)lptr)[1];

    for (int c = 0; c < QDP_N; c += 512) {
        // issue next chunk's loads before touching cur (overlap with ballots)
        const int pc = (c + 512 < QDP_N) ? (c + 512) : 0;   // clamped; unused on last iter
        const float* nptr = z1 + pc + 8 * lane;
        float4 nxtA = ((const float4*)nptr)[0];
        float4 nxtB = ((const float4*)nptr)[1];

        const bool m0 = fabsf(curA.x - zq) < QDP_DISZ;
        const bool m1 = fabsf(curA.y - zq) < QDP_DISZ;
        const bool m2 = fabsf(curA.z - zq) < QDP_DISZ;
        const bool m3 = fabsf(curA.w - zq) < QDP_DISZ;
        const bool m4 = fabsf(curB.x - zq) < QDP_DISZ;
        const bool m5 = fabsf(curB.y - zq) < QDP_DISZ;
        const bool m6 = fabsf(curB.z - zq) < QDP_DISZ;
        const bool m7 = fabsf(curB.w - zq) < QDP_DISZ;

        const unsigned long long b0 = __ballot(m0);
        const unsigned long long b1 = __ballot(m1);
        const unsigned long long b2 = __ballot(m2);
        const unsigned long long b3 = __ballot(m3);
        const unsigned long long b4 = __ballot(m4);
        const unsigned long long b5 = __ballot(m5);
        const unsigned long long b6 = __ballot(m6);
        const unsigned long long b7 = __ballot(m7);
        const unsigned long long any = b0|b1|b2|b3|b4|b5|b6|b7;

        if (any) {                                     // wave-uniform
            const int mbyte = (int)m0 | ((int)m1<<1) | ((int)m2<<2) | ((int)m3<<3)
                            | ((int)m4<<4) | ((int)m5<<5) | ((int)m6<<6) | ((int)m7<<7);
            if (cnt == 0) {
                // first match = lowest candidate index = lowest lane with a match,
                // then that lane's lowest j
                const int l0  = (int)__builtin_ctzll(any);
                const int mb0 = __shfl(mbyte, l0);
                firstv = c + 8 * l0 + (int)__builtin_ctz((unsigned)mb0);
            }
            int r = cnt + __popcll(b0 & below) + __popcll(b1 & below)
                        + __popcll(b2 & below) + __popcll(b3 & below)
                        + __popcll(b4 & below) + __popcll(b5 & below)
                        + __popcll(b6 & below) + __popcll(b7 & below);
            const int base = c + 8 * lane;
            if (m0) { if (r < QDP_NS) idx_out[r] = base + 0; r++; }
            if (m1) { if (r < QDP_NS) idx_out[r] = base + 1; r++; }
            if (m2) { if (r < QDP_NS) idx_out[r] = base + 2; r++; }
            if (m3) { if (r < QDP_NS) idx_out[r] = base + 3; r++; }
            if (m4) { if (r < QDP_NS) idx_out[r] = base + 4; r++; }
            if (m5) { if (r < QDP_NS) idx_out[r] = base + 5; r++; }
            if (m6) { if (r < QDP_NS) idx_out[r] = base + 6; r++; }
            if (m7) { if (r < QDP_NS) idx_out[r] = base + 7; r++; }
            cnt += __popcll(b0) + __popcll(b1) + __popcll(b2) + __popcll(b3)
                 + __popcll(b4) + __popcll(b5) + __popcll(b6) + __popcll(b7);
            if (cnt >= QDP_NS) { cnt = QDP_NS; break; }
        }
        curA = nxtA; curB = nxtB;
    }

    // trailing slots [cnt, 64) get the first-match index (0 if no match)
    if (lane >= cnt) idx_out[lane] = firstv;
    if (lane == 0)   out_cnt[wid] = cnt;
}

extern "C" void kernel_launch(void* const* d_in, const int* in_sizes, int n_in,
                              void* d_out, int out_size, void* d_ws, size_t ws_size,
                              hipStream_t stream) {
    const float* xyz1 = (const float*)d_in[0];   // (B,3,N) fp32
    const float* xyz2 = (const float*)d_in[1];   // (B,3,M) fp32
    int* out = (int*)d_out;                      // idx (B*M*64) then pts_cnt (B*M)

    int* out_idx = out;
    int* out_cnt = out + (size_t)QDP_B * QDP_M * QDP_NS;

    const int total_waves = QDP_B * QDP_M;           // 16384
    const int grid = total_waves / 4;                // 4 waves (256 thr) per block

    QueryDepthPoint_kernel<<<grid, 256, 0, stream>>>(xyz1, xyz2, out_idx, out_cnt);
}